// Round 4
// baseline (821.153 us; speedup 1.0000x reference)
//
#include <hip/hip_runtime.h>
#include <hip/hip_bf16.h>

#define NN 100000
#define NE 1600000
// D_H = D_E = D_Q = 64, D_HID = 128, N_GRAPHS = 16

typedef __attribute__((ext_vector_type(8))) unsigned short ushort8v;
typedef __attribute__((ext_vector_type(4))) unsigned short ushort4v;
typedef __attribute__((ext_vector_type(8))) short short8v;
typedef __attribute__((ext_vector_type(4))) float f32x4;

__device__ __forceinline__ float b2f(unsigned short u) {
  return __uint_as_float(((unsigned)u) << 16);
}
// f32 -> bf16 bits, round-to-nearest-even
__device__ __forceinline__ short f2bs(float f) {
  unsigned u = __float_as_uint(f);
  unsigned r = (u + 0x7FFFu + ((u >> 16) & 1u)) >> 16;
  return (short)r;
}

// Qg[g][j] = gate_b1[j] + sum_k q[g][k] * gate_w1[128+k][j]
__global__ void qproj_kernel(const float* __restrict__ q,
                             const float* __restrict__ gw1,
                             const float* __restrict__ gb1,
                             float* __restrict__ Qg) {
  int g = blockIdx.x, j = threadIdx.x;
  float acc = gb1[j];
  for (int k = 0; k < 64; ++k) acc += q[g * 64 + k] * gw1[(128 + k) * 128 + j];
  Qg[g * 128 + j] = acc;
}

// Prepack score_w1 e-part (rows 128..191) into bf16 MFMA A-fragments.
// Fragment (t, ks), lane l=(qg,cl): elem j = sw1[(128+ks*32+qg*8+j)*128 + t*16+cl]
// stored at WtG[(t*2+ks)*64 + l] as short8v.
__global__ __launch_bounds__(1024) void prepack_kernel(
    const float* __restrict__ sw1, short8v* __restrict__ WtG) {
  int tid = threadIdx.x;
  int t = tid >> 7, ks = (tid >> 6) & 1, lane = tid & 63;
  int qg = lane >> 4, cl = lane & 15;
  short8v fr;
#pragma unroll
  for (int j = 0; j < 8; ++j)
    fr[j] = f2bs(sw1[(128 + ks * 32 + qg * 8 + j) * 128 + t * 16 + cl]);
  WtG[tid] = fr;
}

// Node projections: [N x 64] @ [64 x 512] -> bf16
// SRCP[N][256]=(Ga|Sa), DSTP[N][256]=(Gb|Sb)
__global__ __launch_bounds__(256) void nodeproj_kernel(
    const float* __restrict__ h, const float* __restrict__ gw1,
    const float* __restrict__ sw1, __hip_bfloat16* __restrict__ SRCP,
    __hip_bfloat16* __restrict__ DSTP) {
  __shared__ float hs[64][64];   // [k][n]
  __shared__ float Ws[64][128];  // [k][c]
  int part = blockIdx.y;
  const float* W = (part & 1) ? sw1 : gw1;
  int roff = (part >= 2) ? 64 : 0;
  __hip_bfloat16* outp = (part >= 2) ? DSTP : SRCP;
  int coff = (part & 1) ? 128 : 0;
  int n0 = blockIdx.x * 64;
  int t = threadIdx.x;

  {
    int n = t & 63, kc = t >> 6;
    int gn = n0 + n;
#pragma unroll
    for (int i = 0; i < 4; ++i) {
      int k = kc * 16 + i * 4;
      float4 hv = make_float4(0.f, 0.f, 0.f, 0.f);
      if (gn < NN) hv = *(const float4*)&h[gn * 64 + k];
      hs[k + 0][n] = hv.x; hs[k + 1][n] = hv.y;
      hs[k + 2][n] = hv.z; hs[k + 3][n] = hv.w;
    }
  }
  {
    const float* Wb = W + roff * 128;
    float* wsf = &Ws[0][0];
#pragma unroll
    for (int i = 0; i < 8; ++i) {
      int flat = (i * 256 + t) * 4;
      *(float4*)&wsf[flat] = *(const float4*)&Wb[flat];
    }
  }
  __syncthreads();

  int tx = t & 31, ty = t >> 5;
  float acc[8][4] = {};
#pragma unroll 4
  for (int k = 0; k < 64; ++k) {
    float hn[8];
    *(float4*)&hn[0] = *(const float4*)&hs[k][ty * 8];
    *(float4*)&hn[4] = *(const float4*)&hs[k][ty * 8 + 4];
    float wv[4];
#pragma unroll
    for (int i = 0; i < 4; ++i) wv[i] = Ws[k][tx + 32 * i];
#pragma unroll
    for (int j = 0; j < 8; ++j)
#pragma unroll
      for (int i = 0; i < 4; ++i) acc[j][i] += hn[j] * wv[i];
  }
#pragma unroll
  for (int j = 0; j < 8; ++j) {
    int gn = n0 + ty * 8 + j;
    if (gn < NN) {
#pragma unroll
      for (int i = 0; i < 4; ++i)
        outp[(size_t)gn * 256 + coff + tx + 32 * i] = __float2bfloat16(acc[j][i]);
    }
  }
}

// Edge kernel v2: 256 edges/block, 4 waves x 64 edges.
// score: C^T = (Wt)^T-frag-as-A x e-frag-as-B -> lane cl owns edge cl,
// dims 16t+qg*4+i; epilogue gathers are 8B ushort4 loads. Fused exp +
// atomicAdd(nsum); writes exp(raw) to out.
__global__ __launch_bounds__(256) void edge_kernel(
    const float* __restrict__ e, const int* __restrict__ eidx,
    const int* __restrict__ ebat, const __hip_bfloat16* __restrict__ SRCP,
    const __hip_bfloat16* __restrict__ DSTP, const float* __restrict__ Qg,
    const short8v* __restrict__ WtG, const float* __restrict__ sb1,
    const float* __restrict__ gw2, const float* __restrict__ gb2,
    const float* __restrict__ sw2, const float* __restrict__ sb2,
    float* __restrict__ out, float* __restrict__ nsum) {
  __shared__ short8v WtS[1024];  // 16 KB
  __shared__ float gateLDS[256];
  const int tid = threadIdx.x;
  const int w = tid >> 6, lane = tid & 63;
  const int qg = lane >> 4, cl = lane & 15;
  const int EB = blockIdx.x * 256 + w * 64;
  const unsigned short* SU = (const unsigned short*)SRCP;
  const unsigned short* DU = (const unsigned short*)DSTP;
  const float sb2v = sb2[0], gb2v = gb2[0];

  {  // stage prepacked W fragments into LDS (coalesced 16B)
    const f32x4* s4 = (const f32x4*)WtG;
    f32x4* d4 = (f32x4*)WtS;
#pragma unroll
    for (int i = 0; i < 4; ++i) d4[tid + i * 256] = s4[tid + i * 256];
  }

  // ---- gate phase: lane = edge EB+lane, FULL 128 dims ----
  {
    int E = EB + lane;
    int src = eidx[E], dst = eidx[NE + E], g = ebat[E];
    const ushort8v* sr = (const ushort8v*)(SU + (size_t)src * 256);
    const ushort8v* dr = (const ushort8v*)(DU + (size_t)dst * 256);
    const f32x4* qv = (const f32x4*)(Qg + g * 128);
    const f32x4* w2 = (const f32x4*)gw2;
    float gacc = 0.f;
#pragma unroll
    for (int jo = 0; jo < 16; ++jo) {
      ushort8v ga = sr[jo], gb = dr[jo];
#pragma unroll
      for (int half = 0; half < 2; ++half) {
        f32x4 qq = qv[2 * jo + half];
        f32x4 ww = w2[2 * jo + half];
#pragma unroll
        for (int ii = 0; ii < 4; ++ii) {
          float x = b2f(ga[half * 4 + ii]) + b2f(gb[half * 4 + ii]) + qq[ii];
          gacc = fmaf(fmaxf(x, 0.f), ww[ii], gacc);
        }
      }
    }
    gateLDS[tid] = 1.f / (1.f + __expf(-(gacc + gb2v)));
  }
  __syncthreads();

  // ---- load e fragments for all 4 row-tiles (lane cl = edge cl) ----
  short8v a0[4], a1[4];
  int srcv[4], dstv[4];
#pragma unroll
  for (int rt = 0; rt < 4; ++rt) {
    int erow = EB + rt * 16 + cl;
    srcv[rt] = eidx[erow];
    dstv[rt] = eidx[NE + erow];
    const float* ap = e + (size_t)erow * 64 + qg * 8;
    f32x4 f0 = __builtin_nontemporal_load((const f32x4*)(ap + 0));
    f32x4 f1 = __builtin_nontemporal_load((const f32x4*)(ap + 4));
    f32x4 f2 = __builtin_nontemporal_load((const f32x4*)(ap + 32));
    f32x4 f3 = __builtin_nontemporal_load((const f32x4*)(ap + 36));
    short8v x0, x1;
    x0[0] = f2bs(f0.x); x0[1] = f2bs(f0.y); x0[2] = f2bs(f0.z); x0[3] = f2bs(f0.w);
    x0[4] = f2bs(f1.x); x0[5] = f2bs(f1.y); x0[6] = f2bs(f1.z); x0[7] = f2bs(f1.w);
    x1[0] = f2bs(f2.x); x1[1] = f2bs(f2.y); x1[2] = f2bs(f2.z); x1[3] = f2bs(f2.w);
    x1[4] = f2bs(f3.x); x1[5] = f2bs(f3.y); x1[6] = f2bs(f3.z); x1[7] = f2bs(f3.w);
    a0[rt] = x0; a1[rt] = x1;
  }

  // ---- t-outer MFMA + epilogue ----
  float part[4] = {0.f, 0.f, 0.f, 0.f};
#pragma unroll 2
  for (int t = 0; t < 8; ++t) {
    short8v Aw0 = WtS[(t * 2 + 0) * 64 + lane];
    short8v Aw1 = WtS[(t * 2 + 1) * 64 + lane];
    f32x4 b1v = *(const f32x4*)&sb1[t * 16 + qg * 4];
    f32x4 w2v = *(const f32x4*)&sw2[t * 16 + qg * 4];
    int col = 128 + t * 16 + qg * 4;
#pragma unroll
    for (int rt = 0; rt < 4; ++rt) {
      ushort4v sa = *(const ushort4v*)&SU[(size_t)srcv[rt] * 256 + col];
      ushort4v sb = *(const ushort4v*)&DU[(size_t)dstv[rt] * 256 + col];
      f32x4 acc = (f32x4){0.f, 0.f, 0.f, 0.f};
      acc = __builtin_amdgcn_mfma_f32_16x16x32_bf16(Aw0, a0[rt], acc, 0, 0, 0);
      acc = __builtin_amdgcn_mfma_f32_16x16x32_bf16(Aw1, a1[rt], acc, 0, 0, 0);
#pragma unroll
      for (int i = 0; i < 4; ++i) {
        float hv = acc[i] + b2f(sa[i]) + b2f(sb[i]) + b1v[i];
        part[rt] = fmaf(fmaxf(hv, 0.f), w2v[i], part[rt]);
      }
    }
  }

  // ---- reduce across qg groups; finalize (exp + atomicAdd) ----
#pragma unroll
  for (int rt = 0; rt < 4; ++rt) {
    float p = part[rt];
    p += __shfl_xor(p, 16, 64);
    p += __shfl_xor(p, 32, 64);
    if (lane < 16) {
      int r = rt * 16 + cl;  // cl == lane here
      float ex = __expf(gateLDS[w * 64 + r] * (p + sb2v));
      out[EB + r] = ex;
      atomicAdd(&nsum[dstv[rt]], ex);
    }
  }
}

__global__ __launch_bounds__(256) void norm_kernel(
    const int* __restrict__ eidx, const float* __restrict__ nodesum,
    float* __restrict__ out) {
  int ee = blockIdx.x * 256 + threadIdx.x;
  int dst = eidx[NE + ee];
  out[ee] = out[ee] / fmaxf(nodesum[dst], 1e-9f);
}

extern "C" void kernel_launch(void* const* d_in, const int* in_sizes, int n_in,
                              void* d_out, int out_size, void* d_ws, size_t ws_size,
                              hipStream_t stream) {
  const float* h   = (const float*)d_in[0];
  const float* e   = (const float*)d_in[1];
  const float* q   = (const float*)d_in[2];
  const int* eidx  = (const int*)d_in[3];
  const int* ebat  = (const int*)d_in[4];
  const float* gw1 = (const float*)d_in[5];
  const float* gb1 = (const float*)d_in[6];
  const float* gw2 = (const float*)d_in[7];
  const float* gb2 = (const float*)d_in[8];
  const float* sw1 = (const float*)d_in[9];
  const float* sb1 = (const float*)d_in[10];
  const float* sw2 = (const float*)d_in[11];
  const float* sb2 = (const float*)d_in[12];
  float* out = (float*)d_out;

  char* ws = (char*)d_ws;
  __hip_bfloat16* SRCP = (__hip_bfloat16*)ws;
  __hip_bfloat16* DSTP = (__hip_bfloat16*)(ws + 51200000);
  float* Qg    = (float*)(ws + 102400000);            // 8 KB
  short8v* WtG = (short8v*)(ws + 102400000 + 8192);   // 16 KB
  float* nsum  = (float*)(ws + 102400000 + 8192 + 16384);

  (void)hipMemsetAsync(nsum, 0, 400000, stream);
  qproj_kernel<<<dim3(16), dim3(128), 0, stream>>>(q, gw1, gb1, Qg);
  prepack_kernel<<<dim3(1), dim3(1024), 0, stream>>>(sw1, WtG);
  nodeproj_kernel<<<dim3(1563, 4), dim3(256), 0, stream>>>(h, gw1, sw1, SRCP, DSTP);
  edge_kernel<<<dim3(NE / 256), dim3(256), 0, stream>>>(
      e, eidx, ebat, SRCP, DSTP, Qg, WtG, sb1, gw2, gb2, sw2, sb2, out, nsum);
  norm_kernel<<<dim3(NE / 256), dim3(256), 0, stream>>>(eidx, nsum, out);
}